// Round 3
// baseline (71.695 us; speedup 1.0000x reference)
//
#include <hip/hip_runtime.h>
#include <stdint.h>

typedef short bf16x8 __attribute__((ext_vector_type(8)));
typedef float f32x4 __attribute__((ext_vector_type(4)));

#define NROWS 8192
#define DIM   128
// sqrt(10/ln2): dot of scaled z gives 10*cos/ln2, so exp2(dot)=exp(10*cos)
#define ZSCALE 3.7982824f
#define LN2F  0.6931471805599453f

__device__ __forceinline__ unsigned short f32_to_bf16_bits(float x) {
  union { float f; uint32_t u; } v; v.f = x;
  uint32_t r = v.u + 0x7FFFu + ((v.u >> 16) & 1u);  // RNE
  return (unsigned short)(r >> 16);
}

#define GLOAD_LDS16(gsrc, ldst)                                      \
  __builtin_amdgcn_global_load_lds(                                  \
      (const __attribute__((address_space(1))) unsigned int*)(gsrc), \
      (__attribute__((address_space(3))) unsigned int*)(ldst), 16, 0, 0)

// K0: one-time W transpose to bf16 (Wt[n][k] = W[k][n]) + zero accumulators.
// Coalesced writes along k; strided reads are L2-resident (64 KB).
__global__ __launch_bounds__(256) void k_wprep(const float* __restrict__ W,
                                               unsigned short* __restrict__ Wt,
                                               float* __restrict__ sumexp,
                                               float* __restrict__ topacc) {
  const int idx = blockIdx.x * 256 + threadIdx.x;  // 0..16383
  const int n = idx >> 7, k = idx & 127;
  Wt[idx] = f32_to_bf16_bits(W[k * DIM + n]);
  if (idx < NROWS) sumexp[idx] = 0.f;
  if (idx == 0) topacc[0] = 0.f;
}

// K1: z = bf16( ZSCALE * normalize(anchor @ W + bias) )
// 512 one-wave blocks; wave owns 16 output rows, all 128 cols.
// B-frags are contiguous bf16x8 loads from Wt (L2-resident).
__global__ __launch_bounds__(64) void k_proj_norm(
    const float* __restrict__ anchor, const unsigned short* __restrict__ Wt,
    const float* __restrict__ bias, unsigned short* __restrict__ z) {
  const int l = threadIdx.x & 63, g = l >> 4, q = l & 15;
  const int rowbase = blockIdx.x * 16;

  f32x4 acc[8];
#pragma unroll
  for (int tj = 0; tj < 8; ++tj) acc[tj] = (f32x4){0.f, 0.f, 0.f, 0.f};

#pragma unroll
  for (int ks = 0; ks < 4; ++ks) {
    // A frag: lane holds anchor[rowbase+q][ks*32+g*8 .. +8] (vector f32 loads)
    const float* ap = anchor + (size_t)(rowbase + q) * DIM + ks * 32 + g * 8;
    const f32x4 a0 = *(const f32x4*)ap, a1 = *(const f32x4*)(ap + 4);
    bf16x8 a;
#pragma unroll
    for (int e = 0; e < 4; ++e) {
      a[e] = (short)f32_to_bf16_bits(a0[e]);
      a[4 + e] = (short)f32_to_bf16_bits(a1[e]);
    }
#pragma unroll
    for (int tj = 0; tj < 8; ++tj) {
      // B frag: Wt[col=tj*16+q][k=ks*32+g*8..+8] contiguous
      const bf16x8 b =
          *(const bf16x8*)(Wt + (size_t)(tj * 16 + q) * DIM + ks * 32 + g * 8);
      acc[tj] = __builtin_amdgcn_mfma_f32_16x16x32_bf16(a, b, acc[tj], 0, 0, 0);
    }
  }

  // C/D layout: col = q, row = 4*g + r
  float sumsq[4] = {0.f, 0.f, 0.f, 0.f};
#pragma unroll
  for (int tj = 0; tj < 8; ++tj) {
    float bv = bias[tj * 16 + q];
#pragma unroll
    for (int r = 0; r < 4; ++r) {
      acc[tj][r] += bv;
      sumsq[r] += acc[tj][r] * acc[tj][r];
    }
  }
#pragma unroll
  for (int r = 0; r < 4; ++r) {
#pragma unroll
    for (int m = 1; m < 16; m <<= 1) sumsq[r] += __shfl_xor(sumsq[r], m, 64);
  }
  float inv[4];
#pragma unroll
  for (int r = 0; r < 4; ++r) inv[r] = ZSCALE / fmaxf(sqrtf(sumsq[r]), 1e-12f);

#pragma unroll
  for (int tj = 0; tj < 8; ++tj)
#pragma unroll
    for (int r = 0; r < 4; ++r)
      z[(size_t)(rowbase + 4 * g + r) * DIM + tj * 16 + q] =
          f32_to_bf16_bits(acc[tj][r] * inv[r]);
}

// K2: fused Z @ Z^T -> exp2 -> row sums (+ diag skip, + positive-pair capture)
// grid = 64 i-blocks (128 rows) * 8 j-slices of 8 chunks; waves split i.
// Double-buffered LDS. Per-chunk schedule (KEY: all ds_reads precede the
// gload_lds issue in program order, so no compiler vmcnt-before-ds_read;
// the exp2 epilogue then covers the staging latency before the barrier):
//   {ds_read + MFMA}(cur) -> STAGE(next) -> epilogue(exp2) -> __syncthreads.
__global__ __launch_bounds__(256) void k_simloss(
    const unsigned short* __restrict__ z, float* __restrict__ sumexp,
    float* __restrict__ topacc) {
  __shared__ __align__(16) unsigned short lz[2 * 128 * 128];  // 2 x 32 KB
  const int t = threadIdx.x;
  const int wv = t >> 6, l = t & 63, g = l >> 4, q = l & 15;
  const int iblk = (int)blockIdx.x >> 3, slice = (int)blockIdx.x & 7;
  const int ib = iblk * 128;

  // A frags: wave holds its 32 i-rows: lane = row ib+wv*32+ti*16+q
  bf16x8 afr[2][4];
#pragma unroll
  for (int ti = 0; ti < 2; ++ti)
#pragma unroll
    for (int ks = 0; ks < 4; ++ks)
      afr[ti][ks] = *(const bf16x8*)(z + (size_t)(ib + wv * 32 + ti * 16 + q) * DIM +
                                     ks * 32 + g * 8);

  float sums[2][4];
#pragma unroll
  for (int ti = 0; ti < 2; ++ti)
#pragma unroll
    for (int r = 0; r < 4; ++r) sums[ti][r] = 0.f;
  float topv = 0.f;

  const int diag_chunk = iblk;             // 128-row iblock == 128-col chunk
  const int pos_chunk = (iblk + 32) & 63;  // +4096 cols = +32 chunks
  const int ch0 = slice * 8;

// stage chunk ch_ into LDS buffer at byte offset bufofs (linear dest, swizzled src)
#define STAGE(bufofs, ch_)                                                \
  _Pragma("unroll") for (int it = 0; it < 8; ++it) {                      \
    const int n = it * 256 + t;                                           \
    const int row = n >> 4, c = n & 15;                                   \
    const char* src = (const char*)z + ((size_t)((ch_)*128 + row) << 8) + \
                      ((c ^ (row & 7)) << 4);                             \
    GLOAD_LDS16(src, (char*)lz + (bufofs) + it * 4096 + wv * 1024);       \
  }

  STAGE(0, ch0);
  __syncthreads();  // buf0 ready
  int cur = 0;

  for (int ch = ch0; ch < ch0 + 8; ++ch) {
    // ---- phase 1: ds_read B-frags + MFMA on current buffer ----
    f32x4 acc[2][8];
#pragma unroll
    for (int ti = 0; ti < 2; ++ti)
#pragma unroll
      for (int tj = 0; tj < 8; ++tj) acc[ti][tj] = (f32x4){0.f, 0.f, 0.f, 0.f};

    const char* buf = (const char*)lz + (cur ? 32768 : 0);
#pragma unroll
    for (int tj = 0; tj < 8; ++tj) {
      const int row_l = tj * 16 + q;
      bf16x8 bfr[4];
#pragma unroll
      for (int ks = 0; ks < 4; ++ks)
        bfr[ks] = *(const bf16x8*)(buf + row_l * 256 +
                                   (((ks * 4 + g) ^ (row_l & 7)) << 4));
#pragma unroll
      for (int ti = 0; ti < 2; ++ti)
#pragma unroll
        for (int ks = 0; ks < 4; ++ks)
          acc[ti][tj] = __builtin_amdgcn_mfma_f32_16x16x32_bf16(
              afr[ti][ks], bfr[ks], acc[ti][tj], 0, 0, 0);
    }

    // ---- phase 2: issue next chunk's staging (after ALL LDS reads) ----
    if (ch + 1 < ch0 + 8) STAGE(cur ? 0 : 32768, ch + 1);

    // ---- phase 3: epilogue (covers staging latency) ----
    const bool dg = (ch == diag_chunk), ps = (ch == pos_chunk);
    if (dg || ps) {
#pragma unroll
      for (int ti = 0; ti < 2; ++ti)
#pragma unroll
        for (int tj = 0; tj < 8; ++tj)
#pragma unroll
          for (int r = 0; r < 4; ++r) {
            const float d = acc[ti][tj][r];
            const int iloc = wv * 32 + ti * 16 + 4 * g + r;
            const int cloc = tj * 16 + q;
            float e = __builtin_amdgcn_exp2f(d);
            if (dg && cloc == iloc) e = 0.f;    // j == i: excluded from bottom
            if (ps && cloc == iloc) topv += d;  // j == (i+4096)%8192
            sums[ti][r] += e;
          }
    } else {
#pragma unroll
      for (int ti = 0; ti < 2; ++ti)
#pragma unroll
        for (int tj = 0; tj < 8; ++tj)
#pragma unroll
          for (int r = 0; r < 4; ++r)
            sums[ti][r] += __builtin_amdgcn_exp2f(acc[ti][tj][r]);
    }

    __syncthreads();  // drains vmcnt: next buffer staged, all reads done
    cur ^= 1;
  }
#undef STAGE

  // reduce partial row-sums across the 16 col-lanes of each group
#pragma unroll
  for (int ti = 0; ti < 2; ++ti)
#pragma unroll
    for (int r = 0; r < 4; ++r) {
#pragma unroll
      for (int m = 1; m < 16; m <<= 1)
        sums[ti][r] += __shfl_xor(sums[ti][r], m, 64);
    }
  if (q == 0) {
#pragma unroll
    for (int ti = 0; ti < 2; ++ti)
#pragma unroll
      for (int r = 0; r < 4; ++r)
        atomicAdd(&sumexp[ib + wv * 32 + ti * 16 + 4 * g + r], sums[ti][r]);
  }

  // top-term: full wave reduce, one atomic per wave
#pragma unroll
  for (int m = 1; m < 64; m <<= 1) topv += __shfl_xor(topv, m, 64);
  if (l == 0) atomicAdd(topacc, topv);
}

// K3: loss = (sum_i ln(bottom_i) - ln2 * sum_top) / (b-1)
__global__ __launch_bounds__(256) void k_final(const float* __restrict__ sumexp,
                                               const float* __restrict__ topacc,
                                               float* __restrict__ out) {
  __shared__ float red[4];
  const int t = threadIdx.x;
  float s = 0.f;
  for (int r = t; r < NROWS; r += 256) s += logf(sumexp[r]);
#pragma unroll
  for (int m = 1; m < 64; m <<= 1) s += __shfl_xor(s, m, 64);
  if ((t & 63) == 0) red[t >> 6] = s;
  __syncthreads();
  if (t == 0) {
    const float S1 = red[0] + red[1] + red[2] + red[3];
    out[0] = (S1 - LN2F * topacc[0]) * (1.0f / (float)(NROWS - 1));
  }
}

extern "C" void kernel_launch(void* const* d_in, const int* in_sizes, int n_in,
                              void* d_out, int out_size, void* d_ws, size_t ws_size,
                              hipStream_t stream) {
  const float* anchor = (const float*)d_in[0];
  const float* W = (const float*)d_in[1];
  const float* bias = (const float*)d_in[2];
  float* out = (float*)d_out;

  char* ws = (char*)d_ws;
  unsigned short* z = (unsigned short*)ws;                         // 2 MB bf16 [8192][128]
  float* sumexp = (float*)(ws + (size_t)2 * 1024 * 1024);          // 32 KB
  float* topacc = (float*)(ws + (size_t)2 * 1024 * 1024 + 32768);  // 4 B
  unsigned short* Wt = (unsigned short*)(ws + (size_t)2 * 1024 * 1024 + 36864); // 32 KB

  k_wprep<<<dim3(64), dim3(256), 0, stream>>>(W, Wt, sumexp, topacc);
  k_proj_norm<<<dim3(NROWS / 16), dim3(64), 0, stream>>>(anchor, Wt, bias, z);
  k_simloss<<<dim3((NROWS / 128) * 8), dim3(256), 0, stream>>>(z, sumexp, topacc);
  k_final<<<dim3(1), dim3(256), 0, stream>>>(sumexp, topacc, out);
}

// Round 4
// 64.069 us; speedup vs baseline: 1.1190x; 1.1190x over previous
//
#include <hip/hip_runtime.h>
#include <stdint.h>

typedef short bf16x8 __attribute__((ext_vector_type(8)));
typedef float f32x4 __attribute__((ext_vector_type(4)));

#define NROWS 8192
#define DIM   128
// sqrt(10/ln2): dot of scaled z gives 10*cos/ln2, so exp2(dot)=exp(10*cos)
#define ZSCALE 3.7982824f
#define LN2F  0.6931471805599453f

__device__ __forceinline__ unsigned short f32_to_bf16_bits(float x) {
  union { float f; uint32_t u; } v; v.f = x;
  uint32_t r = v.u + 0x7FFFu + ((v.u >> 16) & 1u);  // RNE
  return (unsigned short)(r >> 16);
}

// K0: one-time W transpose to bf16 (Wt[n][k] = W[k][n]) + zero accumulators.
__global__ __launch_bounds__(256) void k_wprep(const float* __restrict__ W,
                                               unsigned short* __restrict__ Wt,
                                               float* __restrict__ sumexp,
                                               float* __restrict__ topacc) {
  const int idx = blockIdx.x * 256 + threadIdx.x;  // 0..16383
  const int n = idx >> 7, k = idx & 127;
  Wt[idx] = f32_to_bf16_bits(W[k * DIM + n]);
  if (idx < NROWS) sumexp[idx] = 0.f;
  if (idx == 0) topacc[0] = 0.f;
}

// K1: z = bf16( ZSCALE * normalize(anchor @ W + bias) )
// 128 blocks x 4 waves; wave owns 16 output rows, all 128 cols.
// B-frags are contiguous bf16x8 loads from Wt (L2-resident).
__global__ __launch_bounds__(256) void k_proj_norm(
    const float* __restrict__ anchor, const unsigned short* __restrict__ Wt,
    const float* __restrict__ bias, unsigned short* __restrict__ z) {
  const int t = threadIdx.x;
  const int wv = t >> 6, l = t & 63, g = l >> 4, q = l & 15;
  const int rowbase = blockIdx.x * 64 + wv * 16;

  f32x4 acc[8];
#pragma unroll
  for (int tj = 0; tj < 8; ++tj) acc[tj] = (f32x4){0.f, 0.f, 0.f, 0.f};

#pragma unroll
  for (int ks = 0; ks < 4; ++ks) {
    // A frag: lane holds anchor[rowbase+q][ks*32+g*8 .. +8] (vector f32 loads)
    const float* ap = anchor + (size_t)(rowbase + q) * DIM + ks * 32 + g * 8;
    const f32x4 a0 = *(const f32x4*)ap, a1 = *(const f32x4*)(ap + 4);
    bf16x8 a;
#pragma unroll
    for (int e = 0; e < 4; ++e) {
      a[e] = (short)f32_to_bf16_bits(a0[e]);
      a[4 + e] = (short)f32_to_bf16_bits(a1[e]);
    }
#pragma unroll
    for (int tj = 0; tj < 8; ++tj) {
      const bf16x8 b =
          *(const bf16x8*)(Wt + (size_t)(tj * 16 + q) * DIM + ks * 32 + g * 8);
      acc[tj] = __builtin_amdgcn_mfma_f32_16x16x32_bf16(a, b, acc[tj], 0, 0, 0);
    }
  }

  // C/D layout: col = q, row = 4*g + r
  float sumsq[4] = {0.f, 0.f, 0.f, 0.f};
#pragma unroll
  for (int tj = 0; tj < 8; ++tj) {
    float bv = bias[tj * 16 + q];
#pragma unroll
    for (int r = 0; r < 4; ++r) {
      acc[tj][r] += bv;
      sumsq[r] += acc[tj][r] * acc[tj][r];
    }
  }
#pragma unroll
  for (int r = 0; r < 4; ++r) {
#pragma unroll
    for (int m = 1; m < 16; m <<= 1) sumsq[r] += __shfl_xor(sumsq[r], m, 64);
  }
  float inv[4];
#pragma unroll
  for (int r = 0; r < 4; ++r) inv[r] = ZSCALE / fmaxf(sqrtf(sumsq[r]), 1e-12f);

#pragma unroll
  for (int tj = 0; tj < 8; ++tj)
#pragma unroll
    for (int r = 0; r < 4; ++r)
      z[(size_t)(rowbase + 4 * g + r) * DIM + tj * 16 + q] =
          f32_to_bf16_bits(acc[tj][r] * inv[r]);
}

// K2: fused Z @ Z^T -> exp2 -> row sums. NO LDS, NO barriers: z (2 MB) is
// L2-resident, so B-fragments stream directly from global (lane pattern =
// 16 rows x 64B contiguous segments). Waves fully independent; latency is
// hidden by TLP (8 waves/CU). Grid = 32 i-groups (256 rows) x 16 j-blocks
// (512 cols); wave wv owns 64 i-rows, all 4 waves of a block walk the same
// j-block (B re-reads hit L1).
__global__ __launch_bounds__(256) void k_simloss(
    const unsigned short* __restrict__ z, float* __restrict__ sumexp,
    float* __restrict__ topacc) {
  const int t = threadIdx.x;
  const int wv = t >> 6, l = t & 63, g = l >> 4, q = l & 15;
  const int igrp = (int)blockIdx.x >> 4, jbi = (int)blockIdx.x & 15;
  const int r0 = igrp * 256 + wv * 64;   // this wave's 64 i-rows
  const int cb = jbi * 512;              // this block's 512 j-cols

  // A frags: afr[ti][ks] -> row r0+ti*16+q, k = ks*32+g*8..+8
  bf16x8 afr[4][4];
#pragma unroll
  for (int ti = 0; ti < 4; ++ti)
#pragma unroll
    for (int ks = 0; ks < 4; ++ks)
      afr[ti][ks] = *(const bf16x8*)(z + (size_t)(r0 + ti * 16 + q) * DIM +
                                     ks * 32 + g * 8);

  float sums[4][4];  // [ti][r] partial sum-of-exp
#pragma unroll
  for (int ti = 0; ti < 4; ++ti)
#pragma unroll
    for (int r = 0; r < 4; ++r) sums[ti][r] = 0.f;
  float topv = 0.f;

  for (int jt = 0; jt < 16; ++jt) {
    const int c0 = cb + jt * 32;
    // B frags: bfr[tj][ks] -> col-row c0+tj*16+q, contiguous 16B per lane
    bf16x8 bfr[2][4];
#pragma unroll
    for (int tj = 0; tj < 2; ++tj)
#pragma unroll
      for (int ks = 0; ks < 4; ++ks)
        bfr[tj][ks] = *(const bf16x8*)(z + (size_t)(c0 + tj * 16 + q) * DIM +
                                       ks * 32 + g * 8);

    f32x4 acc[4][2];
#pragma unroll
    for (int ti = 0; ti < 4; ++ti)
#pragma unroll
      for (int tj = 0; tj < 2; ++tj) acc[ti][tj] = (f32x4){0.f, 0.f, 0.f, 0.f};
#pragma unroll
    for (int ti = 0; ti < 4; ++ti)
#pragma unroll
      for (int tj = 0; tj < 2; ++tj)
#pragma unroll
        for (int ks = 0; ks < 4; ++ks)
          acc[ti][tj] = __builtin_amdgcn_mfma_f32_16x16x32_bf16(
              afr[ti][ks], bfr[tj][ks], acc[ti][tj], 0, 0, 0);

    // epilogue: e = exp2(d); diag skip / positive capture only in hit tiles
    const bool dg = (c0 >> 6) == (r0 >> 6);                      // tile hits diagonal
    const bool ps = (((c0 + 4096) & 8191) >> 6) == (r0 >> 6);    // tile hits pos pair
    if (dg || ps) {
#pragma unroll
      for (int ti = 0; ti < 4; ++ti)
#pragma unroll
        for (int tj = 0; tj < 2; ++tj)
#pragma unroll
          for (int r = 0; r < 4; ++r) {
            const float d = acc[ti][tj][r];
            const int row_g = r0 + ti * 16 + 4 * g + r;
            const int col_g = c0 + tj * 16 + q;
            float e = __builtin_amdgcn_exp2f(d);
            if (dg && col_g == row_g) e = 0.f;                       // j == i
            if (ps && col_g == ((row_g + 4096) & 8191)) topv += d;   // positive pair
            sums[ti][r] += e;
          }
    } else {
#pragma unroll
      for (int ti = 0; ti < 4; ++ti)
#pragma unroll
        for (int tj = 0; tj < 2; ++tj)
#pragma unroll
          for (int r = 0; r < 4; ++r)
            sums[ti][r] += __builtin_amdgcn_exp2f(acc[ti][tj][r]);
    }
  }

  // reduce partial row-sums across the 16 col-lanes of each group
#pragma unroll
  for (int ti = 0; ti < 4; ++ti)
#pragma unroll
    for (int r = 0; r < 4; ++r) {
#pragma unroll
      for (int m = 1; m < 16; m <<= 1)
        sums[ti][r] += __shfl_xor(sums[ti][r], m, 64);
    }
  if (q == 0) {
#pragma unroll
    for (int ti = 0; ti < 4; ++ti)
#pragma unroll
      for (int r = 0; r < 4; ++r)
        atomicAdd(&sumexp[r0 + ti * 16 + 4 * g + r], sums[ti][r]);
  }

  // top-term: only waves whose j-block contains their rows' positive columns
  if ((((r0 + 4096) & 8191) >> 9) == jbi) {
#pragma unroll
    for (int m = 1; m < 64; m <<= 1) topv += __shfl_xor(topv, m, 64);
    if (l == 0) atomicAdd(topacc, topv);
  }
}

// K3: loss = (sum_i ln(bottom_i) - ln2 * sum_top) / (b-1)
__global__ __launch_bounds__(256) void k_final(const float* __restrict__ sumexp,
                                               const float* __restrict__ topacc,
                                               float* __restrict__ out) {
  __shared__ float red[4];
  const int t = threadIdx.x;
  float s = 0.f;
  for (int r = t; r < NROWS; r += 256) s += logf(sumexp[r]);
#pragma unroll
  for (int m = 1; m < 64; m <<= 1) s += __shfl_xor(s, m, 64);
  if ((t & 63) == 0) red[t >> 6] = s;
  __syncthreads();
  if (t == 0) {
    const float S1 = red[0] + red[1] + red[2] + red[3];
    out[0] = (S1 - LN2F * topacc[0]) * (1.0f / (float)(NROWS - 1));
  }
}

extern "C" void kernel_launch(void* const* d_in, const int* in_sizes, int n_in,
                              void* d_out, int out_size, void* d_ws, size_t ws_size,
                              hipStream_t stream) {
  const float* anchor = (const float*)d_in[0];
  const float* W = (const float*)d_in[1];
  const float* bias = (const float*)d_in[2];
  float* out = (float*)d_out;

  char* ws = (char*)d_ws;
  unsigned short* z = (unsigned short*)ws;                         // 2 MB bf16 [8192][128]
  float* sumexp = (float*)(ws + (size_t)2 * 1024 * 1024);          // 32 KB
  float* topacc = (float*)(ws + (size_t)2 * 1024 * 1024 + 32768);  // 4 B
  unsigned short* Wt = (unsigned short*)(ws + (size_t)2 * 1024 * 1024 + 36864); // 32 KB

  k_wprep<<<dim3(64), dim3(256), 0, stream>>>(W, Wt, sumexp, topacc);
  k_proj_norm<<<dim3(NROWS / 64), dim3(256), 0, stream>>>(anchor, Wt, bias, z);
  k_simloss<<<dim3(32 * 16), dim3(256), 0, stream>>>(z, sumexp, topacc);
  k_final<<<dim3(1), dim3(256), 0, stream>>>(sumexp, topacc, out);
}